// Round 13
// baseline (75.058 us; speedup 1.0000x reference)
//
#include <hip/hip_runtime.h>
#include <hip/hip_bf16.h>

// Problem constants (reference: N=2048, D=512, T=0.1, sigma=1, 4 classes)
#define D 512
#define INV_T 10.0f
#define INF_VAL 1e8f

#define BM 128
#define BK 64
#define KSTEPS (D / BK)   // 8
#define NCHUNK 64         // 64-wide column chunks for partials
#define KRANK 10          // Taylor rank of the RBF kernel (err ~7.5e-7)

typedef short bf16x8 __attribute__((ext_vector_type(8)));
typedef float f32x4 __attribute__((ext_vector_type(4)));

typedef __attribute__((address_space(3))) unsigned int lds_uint;
typedef __attribute__((address_space(1))) unsigned int gbl_uint;

__device__ __forceinline__ void async_copy16(const ushort* gsrc, ushort* ldst) {
  // 64 lanes x 16B -> 1 KB; LDS dest = wave-uniform base + lane*16 (linear)
  __builtin_amdgcn_global_load_lds((const gbl_uint*)gsrc, (lds_uint*)ldst, 16, 0, 0);
}

__device__ inline float wave_reduce_sum(float v) {
#pragma unroll
  for (int off = 32; off > 0; off >>= 1) v += __shfl_xor(v, off);
  return v;
}

__device__ __forceinline__ ushort f2bf(float x) {
  __hip_bfloat16 h = __float2bfloat16(x);
  return *reinterpret_cast<ushort*>(&h);
}

// 1/sqrt(k!) for k = 0..9
__device__ __constant__ float RSQF[KRANK] = {
    1.0f, 1.0f, 0.70710678f, 0.40824829f, 0.20412415f,
    0.09128709f, 0.03726780f, 0.01408591f, 0.00498010f, 0.00166002f};

// phi_k(p) = e^{-p^2/2} * p^k / sqrt(k!);  rbf(r,c) = sum_k phi_k(p_r)phi_k(p_c)
__device__ __forceinline__ void phi_eval(float p, float* phi) {
  float u = __expf(-0.5f * p * p);
  float pw = 1.f;
#pragma unroll
  for (int k = 0; k < KRANK; ++k) {
    phi[k] = u * pw * RSQF[k];
    pw *= p;
  }
}

// -------------------------------------------------------------------------
// normcast only (proven R5 wave-per-row body): 1024 blocks x 4 rows
__global__ __launch_bounds__(256) void k_prep(const float* __restrict__ zi,
                                              const float* __restrict__ zj,
                                              ushort* __restrict__ zb, int N) {
  int wv = threadIdx.x >> 6, lane = threadIdx.x & 63;
  int row = blockIdx.x * 4 + wv;
  const float* src = (row < N) ? (zi + (size_t)row * D) : (zj + (size_t)(row - N) * D);
  const float4* s4 = reinterpret_cast<const float4*>(src);
  float4 v0 = s4[lane];
  float4 v1 = s4[lane + 64];
  float ss = 0.f;
  ss = fmaf(v0.x, v0.x, ss); ss = fmaf(v0.y, v0.y, ss);
  ss = fmaf(v0.z, v0.z, ss); ss = fmaf(v0.w, v0.w, ss);
  ss = fmaf(v1.x, v1.x, ss); ss = fmaf(v1.y, v1.y, ss);
  ss = fmaf(v1.z, v1.z, ss); ss = fmaf(v1.w, v1.w, ss);
  ss = wave_reduce_sum(ss);
  float sc = 1.0f / fmaxf(sqrtf(ss), 1e-12f);
  ushort4 o0 = {f2bf(v0.x * sc), f2bf(v0.y * sc), f2bf(v0.z * sc), f2bf(v0.w * sc)};
  ushort4 o1 = {f2bf(v1.x * sc), f2bf(v1.y * sc), f2bf(v1.z * sc), f2bf(v1.w * sc)};
  ushort4* dst = reinterpret_cast<ushort4*>(zb + (size_t)row * D);
  dst[lane] = o0;
  dst[lane + 64] = o1;
}

// -------------------------------------------------------------------------
// Single-block stats kernel, 3 phases (deterministic fixed-order reductions):
//  1. T[l][k]  = sum_{i: lab=l} phi_k(p_i)
//  2. sinv[j]  = 1/(2*shalf_j - 1),  shalf_j = sum_k phi_k(p_j) T[l_j][k]
//  3. S[l][k]  = sum_{j: lab=l} phi_k(p_j) sinv_j   (tt_i = sum_k phi_k S[l_i][k])
// Replaces the O(N^2) colsum + tt kernels with O(N*K).
__global__ __launch_bounds__(256) void k_stats(const int* __restrict__ labels,
                                               const float* __restrict__ zpos,
                                               float* __restrict__ sinv,
                                               float* __restrict__ Sg, int N) {
  __shared__ float Tl[4][KRANK];
  __shared__ float red2[4][4 * KRANK];   // [wave][l*KRANK+k]
  __shared__ float sv[2048];
  const int t = threadIdx.x, lane = t & 63, wv = t >> 6;

  // ---- phase 1: T ----
  float part[4][KRANK];
#pragma unroll
  for (int l = 0; l < 4; ++l)
#pragma unroll
    for (int k = 0; k < KRANK; ++k) part[l][k] = 0.f;
  for (int i = t; i < N; i += 256) {
    int l = labels[i];
    float phi[KRANK];
    phi_eval(zpos[i], phi);
#pragma unroll
    for (int l4 = 0; l4 < 4; ++l4) {
      float msk = (l == l4) ? 1.f : 0.f;
#pragma unroll
      for (int k = 0; k < KRANK; ++k) part[l4][k] = fmaf(msk, phi[k], part[l4][k]);
    }
  }
#pragma unroll
  for (int l = 0; l < 4; ++l)
#pragma unroll
    for (int k = 0; k < KRANK; ++k) {
      float v = wave_reduce_sum(part[l][k]);
      if (lane == 0) red2[wv][l * KRANK + k] = v;
    }
  __syncthreads();
  if (t < 4 * KRANK)
    Tl[t / KRANK][t % KRANK] =
        red2[0][t] + red2[1][t] + red2[2][t] + red2[3][t];
  __syncthreads();

  // ---- phase 2: sinv ----
  for (int j = t; j < N; j += 256) {
    int l = labels[j];
    float phi[KRANK];
    phi_eval(zpos[j], phi);
    float sh = 0.f;
#pragma unroll
    for (int k = 0; k < KRANK; ++k) sh = fmaf(phi[k], Tl[l][k], sh);
    float s = 1.0f / (2.0f * sh - 1.0f);
    sv[j] = s;
    sinv[j] = s;
  }
  __syncthreads();

  // ---- phase 3: S ----
#pragma unroll
  for (int l = 0; l < 4; ++l)
#pragma unroll
    for (int k = 0; k < KRANK; ++k) part[l][k] = 0.f;
  for (int j = t; j < N; j += 256) {
    int l = labels[j];
    float phi[KRANK];
    phi_eval(zpos[j], phi);
    float w = sv[j];
#pragma unroll
    for (int l4 = 0; l4 < 4; ++l4) {
      float msk = (l == l4) ? w : 0.f;
#pragma unroll
      for (int k = 0; k < KRANK; ++k) part[l4][k] = fmaf(msk, phi[k], part[l4][k]);
    }
  }
#pragma unroll
  for (int l = 0; l < 4; ++l)
#pragma unroll
    for (int k = 0; k < KRANK; ++k) {
      float v = wave_reduce_sum(part[l][k]);
      if (lane == 0) red2[wv][l * KRANK + k] = v;
    }
  __syncthreads();
  if (t < 4 * KRANK)
    Sg[t] = red2[0][t] + red2[1][t] + red2[2][t] + red2[3][t];
}

// -------------------------------------------------------------------------
// Main GEMM — byte-for-byte the R4 kernel (measured 41 us, best of 9
// configs). Full-matrix 128x128 tiles, 1024 blocks, BK=64, single-buffered
// 32 KB LDS, stage -> sync -> compute -> sync; 4 waves (2x2), 64x64 each;
// 1D %8 XCD swizzle; linear LDS dest + pre-swizzled source slot, read-side
// XOR (rule #21 pair, measured 0 conflicts). Fused epilogue: fixed-max
// softmax exp-sum + label/RBF-weighted cross; partials at chunk ct*2+wc.
__global__ __launch_bounds__(256, 4) void k_gemm(
    const ushort* __restrict__ zb, const int* __restrict__ labels,
    const float* __restrict__ zpos, const float* __restrict__ sinv,
    float* __restrict__ s_ws, float* __restrict__ c_ws, int N) {
  __shared__ __align__(16) ushort As[BM * BK];   // 16 KB, row stride 128B (8 slots)
  __shared__ __align__(16) ushort Bs[BM * BK];   // 16 KB

  const int tid = threadIdx.x;
  const int lane = tid & 63;
  const int wv = tid >> 6;        // 0..3
  const int wr = wv >> 1;         // wave row quadrant
  const int wc = wv & 1;          // wave col quadrant
  const int colq = lane & 15;     // frag col / A-frag row
  const int laneg = lane >> 4;    // k-group

  // XCD-aware swizzle (1024 blocks, 8 XCDs, bijective since 1024 % 8 == 0)
  const int bid = blockIdx.x;
  const int L = (bid & 7) * 128 + (bid >> 3);
  const int rt = L >> 5;          // 0..31
  const int ct = L & 31;          // 0..31
  const int rowBase = rt * BM;
  const int colBase = ct * BM;
  const int twoN = 2 * N;

  // staging geometry: 1 inst = 8 rows x 128B; lane -> row lane>>3, slot lane&7.
  // LDS is linear; SOURCE is pre-swizzled so that read-side XOR finds it.
  const int srow = lane >> 3;
  const int sslot = (lane & 7) ^ srow;

  f32x4 acc[4][4] = {};

  for (int kt = 0; kt < KSTEPS; ++kt) {
    // ---- stage A & B tiles (each wave: rows [wv*32, wv*32+32) of both) ----
#pragma unroll
    for (int q = 0; q < 4; ++q) {
      int rloc = wv * 32 + q * 8;
      async_copy16(zb + (size_t)(rowBase + rloc + srow) * D + kt * BK + sslot * 8,
                   (ushort*)As + rloc * BK);
      async_copy16(zb + (size_t)(colBase + rloc + srow) * D + kt * BK + sslot * 8,
                   (ushort*)Bs + rloc * BK);
    }
    __syncthreads();   // drains vmcnt: tiles resident

    // ---- compute: 2 k-substeps of 32 ----
#pragma unroll
    for (int kk = 0; kk < 2; ++kk) {
      bf16x8 a[4], b[4];
      const int slot = (kk * 4 + laneg);
#pragma unroll
      for (int rf = 0; rf < 4; ++rf) {
        int r = wr * 64 + rf * 16 + colq;
        a[rf] = *reinterpret_cast<const bf16x8*>(
            reinterpret_cast<const char*>(As) + r * 128 + (slot ^ (r & 7)) * 16);
      }
#pragma unroll
      for (int cf = 0; cf < 4; ++cf) {
        int c = wc * 64 + cf * 16 + colq;
        b[cf] = *reinterpret_cast<const bf16x8*>(
            reinterpret_cast<const char*>(Bs) + c * 128 + (slot ^ (c & 7)) * 16);
      }
#pragma unroll
      for (int rf = 0; rf < 4; ++rf)
#pragma unroll
        for (int cf = 0; cf < 4; ++cf)
          acc[rf][cf] = __builtin_amdgcn_mfma_f32_16x16x32_bf16(a[rf], b[cf], acc[rf][cf], 0, 0, 0);
    }
    __syncthreads();   // LDS free for next K-tile
  }

  // ---- epilogue ----
  // C layout: col = lane&15, row = (lane>>4)*4 + reg  [m89 verified]
  const int wRowBase = rowBase + wr * 64;
  const int wColBase = colBase + wc * 64;
  const int rmodBase = (wRowBase >= N) ? wRowBase - N : wRowBase;
  const int cmodBase = (wColBase >= N) ? wColBase - N : wColBase;

  float rpos[16];
  unsigned rlab = 0;
#pragma unroll
  for (int rf = 0; rf < 4; ++rf)
#pragma unroll
    for (int rg = 0; rg < 4; ++rg) {
      int idx = rf * 4 + rg;
      int r = rmodBase + rf * 16 + laneg * 4 + rg;
      rpos[idx] = zpos[r];
      rlab |= ((unsigned)labels[r] & 3u) << (idx * 2);
    }

  float s_p[16], c_p[16];
#pragma unroll
  for (int i = 0; i < 16; ++i) { s_p[i] = 0.f; c_p[i] = 0.f; }

#pragma unroll
  for (int cf = 0; cf < 4; ++cf) {
    int jc = cmodBase + cf * 16 + colq;
    int lc = labels[jc];
    float pc = zpos[jc];
    float si = sinv[jc];
    int col = wColBase + cf * 16 + colq;
#pragma unroll
    for (int rf = 0; rf < 4; ++rf)
#pragma unroll
      for (int rg = 0; rg < 4; ++rg) {
        int idx = rf * 4 + rg;
        int row = wRowBase + rf * 16 + laneg * 4 + rg;
        float sim = acc[rf][cf][rg] * INV_T;
        bool diag = (row == col);
        if (diag) sim = -INF_VAL;
        s_p[idx] += __expf(sim - 10.f);        // exp(-1e8)==0: diag drops out
        int lr = (int)((rlab >> (idx * 2)) & 3u);
        if (lr == lc && !diag) {
          float d = rpos[idx] - pc;
          c_p[idx] = fmaf(__expf(-0.5f * d * d) * si, sim, c_p[idx]);
        }
      }
  }

  // reduce each row over the 16 lanes sharing it
#pragma unroll
  for (int idx = 0; idx < 16; ++idx) {
#pragma unroll
    for (int off = 1; off < 16; off <<= 1) {
      s_p[idx] += __shfl_xor(s_p[idx], off);
      c_p[idx] += __shfl_xor(c_p[idx], off);
    }
  }
  if (colq == 0) {
    int m = ct * 2 + wc;      // 64-wide column chunk index
#pragma unroll
    for (int rf = 0; rf < 4; ++rf)
#pragma unroll
      for (int rg = 0; rg < 4; ++rg) {
        int idx = rf * 4 + rg;
        int row = wRowBase + rf * 16 + laneg * 4 + rg;
        s_ws[(size_t)m * twoN + row] = s_p[idx];
        c_ws[(size_t)m * twoN + row] = c_p[idx];
      }
  }
}

// -------------------------------------------------------------------------
// Per-row combine + block partial sum (proven R8 shape), with tt computed
// inline from the rank-K class moments S: tt = sum_k phi_k(p) S[lab][k].
// 64 blocks x 64 rows. partial[a] = cross_a - wsum_a*(10 + log(sum_m s_ws))
__global__ __launch_bounds__(256) void k_combine(const float* __restrict__ s_ws,
                                                 const float* __restrict__ c_ws,
                                                 const float* __restrict__ sinv,
                                                 const float* __restrict__ Sg,
                                                 const int* __restrict__ labels,
                                                 const float* __restrict__ zpos,
                                                 float* __restrict__ bsum, int N) {
  __shared__ float sS[4][64], sC[4][64];
  int b = blockIdx.x, t = threadIdx.x;
  int r = t & 63, g = t >> 6;
  int twoN = 2 * N;
  int a = b * 64 + r;
  float s = 0.f, c = 0.f;
  for (int k = 0; k < NCHUNK / 4; ++k) {
    int m = g * (NCHUNK / 4) + k;
    s += s_ws[(size_t)m * twoN + a];
    c += c_ws[(size_t)m * twoN + a];
  }
  sS[g][r] = s;
  sC[g][r] = c;
  __syncthreads();
  if (t < 64) {
    float st = sS[0][t] + sS[1][t] + sS[2][t] + sS[3][t];
    float ct = sC[0][t] + sC[1][t] + sC[2][t] + sC[3][t];
    int aa = b * 64 + t;
    int ir = (aa >= N) ? aa - N : aa;
    int l = labels[ir];
    float phi[KRANK];
    phi_eval(zpos[ir], phi);
    float tt = 0.f;
#pragma unroll
    for (int k = 0; k < KRANK; ++k) tt = fmaf(phi[k], Sg[l * KRANK + k], tt);
    float lse = 10.f + logf(st);
    float wsum = 2.f * tt - sinv[ir];
    float p = ct - wsum * lse;
    p = wave_reduce_sum(p);
    if (t == 0) bsum[b] = p;
  }
}

// loss = (-1/N) * sum_b bsum[b]
__global__ __launch_bounds__(64) void k_final(const float* __restrict__ bsum,
                                              float* __restrict__ out, int N) {
  float s = bsum[threadIdx.x];
  s = wave_reduce_sum(s);
  if (threadIdx.x == 0) out[0] = (-1.0f / (float)N) * s;
}

extern "C" void kernel_launch(void* const* d_in, const int* in_sizes, int n_in,
                              void* d_out, int out_size, void* d_ws, size_t ws_size,
                              hipStream_t stream) {
  (void)n_in; (void)out_size; (void)ws_size;
  const float* zi = (const float*)d_in[0];
  const float* zj = (const float*)d_in[1];
  const int* labels = (const int*)d_in[2];
  const float* zpos = (const float*)d_in[3];
  float* out = (float*)d_out;

  const int N = in_sizes[2];       // 2048
  const int twoN = 2 * N;

  // workspace: zb bf16[2N*D] | sinv[N] | Sg[4*KRANK] | s_ws[64*2N] | c_ws[64*2N] | bsum[64]
  char* wsb = (char*)d_ws;
  ushort* zb = (ushort*)wsb;                              // 4 MB
  float* sinv = (float*)(wsb + (size_t)twoN * D * 2);
  float* Sg = sinv + N;
  float* s_ws = Sg + 4 * KRANK + 24;                      // pad to 16B-ish
  float* c_ws = s_ws + (size_t)NCHUNK * twoN;             // 1 MB each
  float* bsum = c_ws + (size_t)NCHUNK * twoN;

  k_prep<<<twoN / 4, 256, 0, stream>>>(zi, zj, zb, N);
  k_stats<<<1, 256, 0, stream>>>(labels, zpos, sinv, Sg, N);
  k_gemm<<<(twoN / BM) * (twoN / BM), 256, 0, stream>>>(zb, labels, zpos, sinv, s_ws, c_ws, N);
  k_combine<<<twoN / 64, 256, 0, stream>>>(s_ws, c_ws, sinv, Sg, labels, zpos, bsum, N);
  k_final<<<1, 64, 0, stream>>>(bsum, out, N);
}

// Round 14
// 72.855 us; speedup vs baseline: 1.0302x; 1.0302x over previous
//
#include <hip/hip_runtime.h>
#include <hip/hip_bf16.h>

// Problem constants (reference: N=2048, D=512, T=0.1, sigma=1, 4 classes)
#define D 512
#define INV_T 10.0f
#define INF_VAL 1e8f

#define BM 128
#define BK 64
#define KSTEPS (D / BK)   // 8
#define NCHUNK 64         // 64-wide column chunks for partials
#define KRANK 10          // Taylor rank of the RBF kernel (err ~7.5e-7, R13-validated)

typedef short bf16x8 __attribute__((ext_vector_type(8)));
typedef float f32x4 __attribute__((ext_vector_type(4)));

typedef __attribute__((address_space(3))) unsigned int lds_uint;
typedef __attribute__((address_space(1))) unsigned int gbl_uint;

__device__ __forceinline__ void async_copy16(const ushort* gsrc, ushort* ldst) {
  // 64 lanes x 16B -> 1 KB; LDS dest = wave-uniform base + lane*16 (linear)
  __builtin_amdgcn_global_load_lds((const gbl_uint*)gsrc, (lds_uint*)ldst, 16, 0, 0);
}

__device__ inline float wave_reduce_sum(float v) {
#pragma unroll
  for (int off = 32; off > 0; off >>= 1) v += __shfl_xor(v, off);
  return v;
}

__device__ __forceinline__ ushort f2bf(float x) {
  __hip_bfloat16 h = __float2bfloat16(x);
  return *reinterpret_cast<ushort*>(&h);
}

// 1/sqrt(k!) for k = 0..9
__device__ __constant__ float RSQF[KRANK] = {
    1.0f, 1.0f, 0.70710678f, 0.40824829f, 0.20412415f,
    0.09128709f, 0.03726780f, 0.01408591f, 0.00498010f, 0.00166002f};

// phi_k(p) = e^{-p^2/2} * p^k / sqrt(k!);  rbf(r,c) = sum_k phi_k(p_r)phi_k(p_c)
__device__ __forceinline__ void phi_eval(float p, float* phi) {
  float u = __expf(-0.5f * p * p);
  float pw = 1.f;
#pragma unroll
  for (int k = 0; k < KRANK; ++k) {
    phi[k] = u * pw * RSQF[k];
    pw *= p;
  }
}

// -------------------------------------------------------------------------
// Fused prep. Blocks [0,1024): normcast (proven R5 wave-per-row body).
// Block 1024: the R13-proven 3-phase stats body (runs CONCURRENTLY with
// normcast — reads only labels/zpos) + zeroes the combine ticket.
__global__ __launch_bounds__(256) void k_prep(const float* __restrict__ zi,
                                              const float* __restrict__ zj,
                                              ushort* __restrict__ zb,
                                              const int* __restrict__ labels,
                                              const float* __restrict__ zpos,
                                              float* __restrict__ sinv,
                                              float* __restrict__ Sg,
                                              unsigned int* __restrict__ ticket,
                                              int N) {
  if (blockIdx.x < 1024) {
    // ---- normcast: one row per wave ----
    int wv = threadIdx.x >> 6, lane = threadIdx.x & 63;
    int row = blockIdx.x * 4 + wv;
    const float* src = (row < N) ? (zi + (size_t)row * D) : (zj + (size_t)(row - N) * D);
    const float4* s4 = reinterpret_cast<const float4*>(src);
    float4 v0 = s4[lane];
    float4 v1 = s4[lane + 64];
    float ss = 0.f;
    ss = fmaf(v0.x, v0.x, ss); ss = fmaf(v0.y, v0.y, ss);
    ss = fmaf(v0.z, v0.z, ss); ss = fmaf(v0.w, v0.w, ss);
    ss = fmaf(v1.x, v1.x, ss); ss = fmaf(v1.y, v1.y, ss);
    ss = fmaf(v1.z, v1.z, ss); ss = fmaf(v1.w, v1.w, ss);
    ss = wave_reduce_sum(ss);
    float sc = 1.0f / fmaxf(sqrtf(ss), 1e-12f);
    ushort4 o0 = {f2bf(v0.x * sc), f2bf(v0.y * sc), f2bf(v0.z * sc), f2bf(v0.w * sc)};
    ushort4 o1 = {f2bf(v1.x * sc), f2bf(v1.y * sc), f2bf(v1.z * sc), f2bf(v1.w * sc)};
    ushort4* dst = reinterpret_cast<ushort4*>(zb + (size_t)row * D);
    dst[lane] = o0;
    dst[lane + 64] = o1;
    return;
  }

  // ---- stats block (R13-proven, deterministic fixed-order reductions) ----
  //  1. T[l][k]  = sum_{i: lab=l} phi_k(p_i)
  //  2. sinv[j]  = 1/(2*shalf_j - 1),  shalf_j = sum_k phi_k(p_j) T[l_j][k]
  //  3. S[l][k]  = sum_{j: lab=l} phi_k(p_j) sinv_j
  __shared__ float Tl[4][KRANK];
  __shared__ float red2[4][4 * KRANK];
  __shared__ float sv[2048];
  const int t = threadIdx.x, lane = t & 63, wv = t >> 6;
  if (t == 0) *ticket = 0u;   // re-arm the combine ticket every call

  float part[4][KRANK];
#pragma unroll
  for (int l = 0; l < 4; ++l)
#pragma unroll
    for (int k = 0; k < KRANK; ++k) part[l][k] = 0.f;
  for (int i = t; i < N; i += 256) {
    int l = labels[i];
    float phi[KRANK];
    phi_eval(zpos[i], phi);
#pragma unroll
    for (int l4 = 0; l4 < 4; ++l4) {
      float msk = (l == l4) ? 1.f : 0.f;
#pragma unroll
      for (int k = 0; k < KRANK; ++k) part[l4][k] = fmaf(msk, phi[k], part[l4][k]);
    }
  }
#pragma unroll
  for (int l = 0; l < 4; ++l)
#pragma unroll
    for (int k = 0; k < KRANK; ++k) {
      float v = wave_reduce_sum(part[l][k]);
      if (lane == 0) red2[wv][l * KRANK + k] = v;
    }
  __syncthreads();
  if (t < 4 * KRANK)
    Tl[t / KRANK][t % KRANK] = red2[0][t] + red2[1][t] + red2[2][t] + red2[3][t];
  __syncthreads();

  for (int j = t; j < N; j += 256) {
    int l = labels[j];
    float phi[KRANK];
    phi_eval(zpos[j], phi);
    float sh = 0.f;
#pragma unroll
    for (int k = 0; k < KRANK; ++k) sh = fmaf(phi[k], Tl[l][k], sh);
    float s = 1.0f / (2.0f * sh - 1.0f);
    sv[j] = s;
    sinv[j] = s;
  }
  __syncthreads();

#pragma unroll
  for (int l = 0; l < 4; ++l)
#pragma unroll
    for (int k = 0; k < KRANK; ++k) part[l][k] = 0.f;
  for (int j = t; j < N; j += 256) {
    int l = labels[j];
    float phi[KRANK];
    phi_eval(zpos[j], phi);
    float w = sv[j];
#pragma unroll
    for (int l4 = 0; l4 < 4; ++l4) {
      float msk = (l == l4) ? w : 0.f;
#pragma unroll
      for (int k = 0; k < KRANK; ++k) part[l4][k] = fmaf(msk, phi[k], part[l4][k]);
    }
  }
#pragma unroll
  for (int l = 0; l < 4; ++l)
#pragma unroll
    for (int k = 0; k < KRANK; ++k) {
      float v = wave_reduce_sum(part[l][k]);
      if (lane == 0) red2[wv][l * KRANK + k] = v;
    }
  __syncthreads();
  if (t < 4 * KRANK)
    Sg[t] = red2[0][t] + red2[1][t] + red2[2][t] + red2[3][t];
}

// -------------------------------------------------------------------------
// Main GEMM — byte-for-byte the R4 kernel (reconverged at 40.5 us in R13;
// MfmaUtil 15.4%, FETCH 36.5 MB, 0 bank conflicts). UNTOUCHED this round.
__global__ __launch_bounds__(256, 4) void k_gemm(
    const ushort* __restrict__ zb, const int* __restrict__ labels,
    const float* __restrict__ zpos, const float* __restrict__ sinv,
    float* __restrict__ s_ws, float* __restrict__ c_ws, int N) {
  __shared__ __align__(16) ushort As[BM * BK];   // 16 KB, row stride 128B (8 slots)
  __shared__ __align__(16) ushort Bs[BM * BK];   // 16 KB

  const int tid = threadIdx.x;
  const int lane = tid & 63;
  const int wv = tid >> 6;        // 0..3
  const int wr = wv >> 1;         // wave row quadrant
  const int wc = wv & 1;          // wave col quadrant
  const int colq = lane & 15;     // frag col / A-frag row
  const int laneg = lane >> 4;    // k-group

  // XCD-aware swizzle (1024 blocks, 8 XCDs, bijective since 1024 % 8 == 0)
  const int bid = blockIdx.x;
  const int L = (bid & 7) * 128 + (bid >> 3);
  const int rt = L >> 5;          // 0..31
  const int ct = L & 31;          // 0..31
  const int rowBase = rt * BM;
  const int colBase = ct * BM;
  const int twoN = 2 * N;

  // staging geometry: 1 inst = 8 rows x 128B; lane -> row lane>>3, slot lane&7.
  // LDS is linear; SOURCE is pre-swizzled so that read-side XOR finds it.
  const int srow = lane >> 3;
  const int sslot = (lane & 7) ^ srow;

  f32x4 acc[4][4] = {};

  for (int kt = 0; kt < KSTEPS; ++kt) {
    // ---- stage A & B tiles (each wave: rows [wv*32, wv*32+32) of both) ----
#pragma unroll
    for (int q = 0; q < 4; ++q) {
      int rloc = wv * 32 + q * 8;
      async_copy16(zb + (size_t)(rowBase + rloc + srow) * D + kt * BK + sslot * 8,
                   (ushort*)As + rloc * BK);
      async_copy16(zb + (size_t)(colBase + rloc + srow) * D + kt * BK + sslot * 8,
                   (ushort*)Bs + rloc * BK);
    }
    __syncthreads();   // drains vmcnt: tiles resident

    // ---- compute: 2 k-substeps of 32 ----
#pragma unroll
    for (int kk = 0; kk < 2; ++kk) {
      bf16x8 a[4], b[4];
      const int slot = (kk * 4 + laneg);
#pragma unroll
      for (int rf = 0; rf < 4; ++rf) {
        int r = wr * 64 + rf * 16 + colq;
        a[rf] = *reinterpret_cast<const bf16x8*>(
            reinterpret_cast<const char*>(As) + r * 128 + (slot ^ (r & 7)) * 16);
      }
#pragma unroll
      for (int cf = 0; cf < 4; ++cf) {
        int c = wc * 64 + cf * 16 + colq;
        b[cf] = *reinterpret_cast<const bf16x8*>(
            reinterpret_cast<const char*>(Bs) + c * 128 + (slot ^ (c & 7)) * 16);
      }
#pragma unroll
      for (int rf = 0; rf < 4; ++rf)
#pragma unroll
        for (int cf = 0; cf < 4; ++cf)
          acc[rf][cf] = __builtin_amdgcn_mfma_f32_16x16x32_bf16(a[rf], b[cf], acc[rf][cf], 0, 0, 0);
    }
    __syncthreads();   // LDS free for next K-tile
  }

  // ---- epilogue ----
  // C layout: col = lane&15, row = (lane>>4)*4 + reg  [m89 verified]
  const int wRowBase = rowBase + wr * 64;
  const int wColBase = colBase + wc * 64;
  const int rmodBase = (wRowBase >= N) ? wRowBase - N : wRowBase;
  const int cmodBase = (wColBase >= N) ? wColBase - N : wColBase;

  float rpos[16];
  unsigned rlab = 0;
#pragma unroll
  for (int rf = 0; rf < 4; ++rf)
#pragma unroll
    for (int rg = 0; rg < 4; ++rg) {
      int idx = rf * 4 + rg;
      int r = rmodBase + rf * 16 + laneg * 4 + rg;
      rpos[idx] = zpos[r];
      rlab |= ((unsigned)labels[r] & 3u) << (idx * 2);
    }

  float s_p[16], c_p[16];
#pragma unroll
  for (int i = 0; i < 16; ++i) { s_p[i] = 0.f; c_p[i] = 0.f; }

#pragma unroll
  for (int cf = 0; cf < 4; ++cf) {
    int jc = cmodBase + cf * 16 + colq;
    int lc = labels[jc];
    float pc = zpos[jc];
    float si = sinv[jc];
    int col = wColBase + cf * 16 + colq;
#pragma unroll
    for (int rf = 0; rf < 4; ++rf)
#pragma unroll
      for (int rg = 0; rg < 4; ++rg) {
        int idx = rf * 4 + rg;
        int row = wRowBase + rf * 16 + laneg * 4 + rg;
        float sim = acc[rf][cf][rg] * INV_T;
        bool diag = (row == col);
        if (diag) sim = -INF_VAL;
        s_p[idx] += __expf(sim - 10.f);        // exp(-1e8)==0: diag drops out
        int lr = (int)((rlab >> (idx * 2)) & 3u);
        if (lr == lc && !diag) {
          float d = rpos[idx] - pc;
          c_p[idx] = fmaf(__expf(-0.5f * d * d) * si, sim, c_p[idx]);
        }
      }
  }

  // reduce each row over the 16 lanes sharing it
#pragma unroll
  for (int idx = 0; idx < 16; ++idx) {
#pragma unroll
    for (int off = 1; off < 16; off <<= 1) {
      s_p[idx] += __shfl_xor(s_p[idx], off);
      c_p[idx] += __shfl_xor(c_p[idx], off);
    }
  }
  if (colq == 0) {
    int m = ct * 2 + wc;      // 64-wide column chunk index
#pragma unroll
    for (int rf = 0; rf < 4; ++rf)
#pragma unroll
      for (int rg = 0; rg < 4; ++rg) {
        int idx = rf * 4 + rg;
        int row = wRowBase + rf * 16 + laneg * 4 + rg;
        s_ws[(size_t)m * twoN + row] = s_p[idx];
        c_ws[(size_t)m * twoN + row] = c_p[idx];
      }
  }
}

// -------------------------------------------------------------------------
// Combine + fused final (ticket pattern). 64 blocks x 64 rows.
// partial[a] = cross_a - wsum_a*(10 + log(sum_m s_ws[m][a]));
// tt inline from rank-K class moments (R13-proven).
// Block writes bsum[b]; the block drawing ticket 63 sums bsum[0..63] in
// FIXED order (deterministic) and writes the loss. Ticket zeroed by k_prep
// each call, so every graph replay is identical.
__global__ __launch_bounds__(256) void k_combine(const float* __restrict__ s_ws,
                                                 const float* __restrict__ c_ws,
                                                 const float* __restrict__ sinv,
                                                 const float* __restrict__ Sg,
                                                 const int* __restrict__ labels,
                                                 const float* __restrict__ zpos,
                                                 float* __restrict__ bsum,
                                                 unsigned int* __restrict__ ticket,
                                                 float* __restrict__ out, int N) {
  __shared__ float sS[4][64], sC[4][64];
  int b = blockIdx.x, t = threadIdx.x;
  int r = t & 63, g = t >> 6;
  int twoN = 2 * N;
  int a = b * 64 + r;
  float s = 0.f, c = 0.f;
  for (int k = 0; k < NCHUNK / 4; ++k) {
    int m = g * (NCHUNK / 4) + k;
    s += s_ws[(size_t)m * twoN + a];
    c += c_ws[(size_t)m * twoN + a];
  }
  sS[g][r] = s;
  sC[g][r] = c;
  __syncthreads();
  if (t < 64) {
    float st = sS[0][t] + sS[1][t] + sS[2][t] + sS[3][t];
    float ct = sC[0][t] + sC[1][t] + sC[2][t] + sC[3][t];
    int aa = b * 64 + t;
    int ir = (aa >= N) ? aa - N : aa;
    int l = labels[ir];
    float phi[KRANK];
    phi_eval(zpos[ir], phi);
    float tt = 0.f;
#pragma unroll
    for (int k = 0; k < KRANK; ++k) tt = fmaf(phi[k], Sg[l * KRANK + k], tt);
    float lse = 10.f + logf(st);
    float wsum = 2.f * tt - sinv[ir];
    float p = ct - wsum * lse;
    p = wave_reduce_sum(p);
    if (t == 0) {
      bsum[b] = p;
      __threadfence();                          // publish bsum[b] device-wide
      unsigned tk = atomicAdd(ticket, 1u);      // device-scope by default
      if (tk == 63u) {
        __threadfence();                        // all 63 others' bsum visible
        float tot = 0.f;
        for (int b2 = 0; b2 < 64; ++b2) tot += bsum[b2];   // fixed order
        out[0] = (-1.0f / (float)N) * tot;
      }
    }
  }
}

extern "C" void kernel_launch(void* const* d_in, const int* in_sizes, int n_in,
                              void* d_out, int out_size, void* d_ws, size_t ws_size,
                              hipStream_t stream) {
  (void)n_in; (void)out_size; (void)ws_size;
  const float* zi = (const float*)d_in[0];
  const float* zj = (const float*)d_in[1];
  const int* labels = (const int*)d_in[2];
  const float* zpos = (const float*)d_in[3];
  float* out = (float*)d_out;

  const int N = in_sizes[2];       // 2048
  const int twoN = 2 * N;

  // ws: zb bf16[2N*D] | sinv[N] | Sg[64] | ticket | pad | s_ws[64*2N] | c_ws[64*2N] | bsum[64]
  char* wsb = (char*)d_ws;
  ushort* zb = (ushort*)wsb;                              // 4 MB
  float* sinv = (float*)(wsb + (size_t)twoN * D * 2);
  float* Sg = sinv + N;                                   // 40 used, 64 reserved
  unsigned int* ticket = (unsigned int*)(Sg + 64);
  float* s_ws = (float*)(Sg + 128);                       // 1 MB
  float* c_ws = s_ws + (size_t)NCHUNK * twoN;             // 1 MB
  float* bsum = c_ws + (size_t)NCHUNK * twoN;

  k_prep<<<1025, 256, 0, stream>>>(zi, zj, zb, labels, zpos, sinv, Sg, ticket, N);
  k_gemm<<<(twoN / BM) * (twoN / BM), 256, 0, stream>>>(zb, labels, zpos, sinv, s_ws, c_ws, N);
  k_combine<<<twoN / 64, 256, 0, stream>>>(s_ws, c_ws, sinv, Sg, labels, zpos, bsum, ticket, out, N);
}